// Round 7
// baseline (391.627 us; speedup 1.0000x reference)
//
#include <hip/hip_runtime.h>
#include <hip/hip_bf16.h>
#include <string.h>

#define BB 4
#define CPc 256
#define NN 2304   // 48*48

typedef __attribute__((ext_vector_type(8))) short bf16x8;
typedef __attribute__((ext_vector_type(4))) float f32x4;

__device__ __forceinline__ short f2b(float x) {
    __hip_bfloat16 h = __float2bfloat16(x);
    return *reinterpret_cast<short*>(&h);
}
__device__ __forceinline__ float b2f16(short v) {
    union { float f; unsigned u; } x;
    x.u = ((unsigned)(unsigned short)v) << 16;
    return x.f;
}

// ---------------- K0: convert weights fp32 -> bf16 ----------------
// TWb 16384 | ZWb 16384 | WPb/WGb concat of 64xCr_i, Cr={64,256,512,1024,2048}
// total = 32768 + 2*249856 = 532480 -> grid 2080
__global__ __launch_bounds__(256) void k_wcvt(
    const float* __restrict__ t_w, const float* __restrict__ z_w,
    const float* p0, const float* p1, const float* p2, const float* p3, const float* p4,
    const float* g0, const float* g1, const float* g2, const float* g3, const float* g4,
    short* __restrict__ TWb, short* __restrict__ ZWb,
    short* __restrict__ WPb, short* __restrict__ WGb) {
    int idx = blockIdx.x * 256 + threadIdx.x;
    if (idx < 16384) { TWb[idx] = f2b(t_w[idx]); return; }
    if (idx < 32768) { ZWb[idx - 16384] = f2b(z_w[idx - 16384]); return; }
    int k = idx - 32768;
    bool isP = k < 249856;
    if (!isP) k -= 249856;
    int i, off;
    if (k < 4096)        { i = 0; off = 0; }
    else if (k < 20480)  { i = 1; off = 4096; }
    else if (k < 53248)  { i = 2; off = 20480; }
    else if (k < 118784) { i = 3; off = 53248; }
    else                 { i = 4; off = 118784; }
    const float* s;
    if (isP) s = (i == 0) ? p0 : (i == 1) ? p1 : (i == 2) ? p2 : (i == 3) ? p3 : p4;
    else     s = (i == 0) ? g0 : (i == 1) ? g1 : (i == 2) ? g2 : (i == 3) ? g3 : g4;
    (isP ? WPb : WGb)[k] = f2b(s[k - off]);
}

// ---------------- K1: batched MFMA 1x1 convs, LDS-staged coalesced ----------------
// seg 0: tq[b][n][c]; seg 1..5: pT_i[b][m][c], gTt_i[b][c][m]
// Per 64-k chunk: stage 64m x 64k input tile to LDS (coalesced: lane = m), XOR
// swizzle on k-group column keeps staging writes 2-way (free) and A-frag a
// single aligned ds_read_b128. OOB m-rows stage zeros -> padded outputs are 0.
// grid = 484 blocks (cum {144,288,432,468,480,484}), block = 256
__global__ __launch_bounds__(256) void k_conv(
    const float* __restrict__ persp,
    const float* r0, const float* r1, const float* r2, const float* r3, const float* r4,
    const short* __restrict__ TWb, const short* __restrict__ WPb, const short* __restrict__ WGb,
    short* __restrict__ TQb, short* __restrict__ PTb, short* __restrict__ GTb) {
    const int CUM[7]  = {0, 144, 288, 432, 468, 480, 484};
    const int CRs[6]  = {256, 64, 256, 512, 1024, 2048};
    const int Mus[6]  = {2304, 2304, 2304, 576, 144, 36};
    const int Mps[6]  = {2304, 2304, 2304, 576, 192, 64};
    const int WOFF[6] = {0, 0, 4096, 20480, 53248, 118784};
    const int POFF[6] = {0, 0, 589824, 1179648, 1327104, 1376256};

    __shared__ __align__(16) short s_a[64][72];   // [m][k] bf16, k-group XOR-swizzled

    int blk = blockIdx.x, t = threadIdx.x;
    int w = t >> 6, lane = t & 63, lo = lane & 15, quad = lane >> 4;
    int seg = 0;
#pragma unroll
    for (int s_ = 1; s_ <= 5; ++s_) if (blk >= CUM[s_]) seg = s_;
    int Cr = CRs[seg], M = Mus[seg], Mp = Mps[seg];
    const float* in = (seg == 0) ? persp : (seg == 1) ? r0 : (seg == 2) ? r1 :
                      (seg == 3) ? r2 : (seg == 4) ? r3 : r4;
    const short* wp = (seg == 0) ? TWb : WPb + WOFF[seg];
    const short* wg = WGb + WOFF[seg];
    short* outP = (seg == 0) ? TQb : PTb + POFF[seg];
    short* outG = GTb + POFF[seg];
    bool has_g = (seg != 0);
    int local = blk - CUM[seg];
    int mb = Mp >> 6;
    int b = local / mb, m0 = (local % mb) * 64;

    int ml = t & 63;                     // staged m within tile (lane = contiguous dim)
    int ssw = (ml >> 3) & 7;             // write-side swizzle
    bool mvalid = (m0 + ml) < M;
    const float* inB = in + ((size_t)b * Cr) * M + m0 + ml;

    int mrow = w * 16 + lo;              // A-frag row
    int rsw = (mrow >> 3) & 7;           // read-side swizzle

    f32x4 accP[4], accG[4];
#pragma unroll
    for (int ct = 0; ct < 4; ++ct) {
        accP[ct] = f32x4{0.f, 0.f, 0.f, 0.f};
        accG[ct] = f32x4{0.f, 0.f, 0.f, 0.f};
    }

    for (int kc = 0; kc < Cr; kc += 64) {
        __syncthreads();   // protect previous chunk's readers
#pragma unroll
        for (int r = 0; r < 8; ++r) {
            int kp = (t >> 6) + r * 4;   // k-pair 0..31
            int q = kp >> 2, l = kp & 3;
            float v0 = 0.f, v1 = 0.f;
            if (mvalid) {
                v0 = inB[(size_t)(kc + 2 * kp) * M];
                v1 = inB[(size_t)(kc + 2 * kp + 1) * M];
            }
            short2 pk; pk.x = f2b(v0); pk.y = f2b(v1);
            *(short2*)&s_a[ml][(q ^ ssw) * 8 + l * 2] = pk;
        }
        __syncthreads();
        const bf16x8 fr0 = *(const bf16x8*)&s_a[mrow][8 * (quad ^ rsw)];
        const bf16x8 fr1 = *(const bf16x8*)&s_a[mrow][8 * ((4 + quad) ^ rsw)];
#pragma unroll
        for (int ct = 0; ct < 4; ++ct) {
            const bf16x8 fp0 = *(const bf16x8*)&wp[(size_t)(ct * 16 + lo) * Cr + kc + quad * 8];
            const bf16x8 fp1 = *(const bf16x8*)&wp[(size_t)(ct * 16 + lo) * Cr + kc + 32 + quad * 8];
            accP[ct] = __builtin_amdgcn_mfma_f32_16x16x32_bf16(fr0, fp0, accP[ct], 0, 0, 0);
            accP[ct] = __builtin_amdgcn_mfma_f32_16x16x32_bf16(fr1, fp1, accP[ct], 0, 0, 0);
            if (has_g) {
                const bf16x8 fg0 = *(const bf16x8*)&wg[(size_t)(ct * 16 + lo) * Cr + kc + quad * 8];
                const bf16x8 fg1 = *(const bf16x8*)&wg[(size_t)(ct * 16 + lo) * Cr + kc + 32 + quad * 8];
                accG[ct] = __builtin_amdgcn_mfma_f32_16x16x32_bf16(fg0, fr0, accG[ct], 0, 0, 0);
                accG[ct] = __builtin_amdgcn_mfma_f32_16x16x32_bf16(fg1, fr1, accG[ct], 0, 0, 0);
            }
        }
    }
    // p/tq epilogue: D[m][c], col=lo=c, row=quad*4+rg=m
    int mP = m0 + w * 16 + quad * 4;
#pragma unroll
    for (int ct = 0; ct < 4; ++ct) {
        int c = ct * 16 + lo;
#pragma unroll
        for (int rg = 0; rg < 4; ++rg)
            outP[((size_t)b * Mp + mP + rg) * 64 + c] = f2b(accP[ct][rg]);
    }
    if (has_g) {
        // g epilogue: D[c][m], col=lo=m, row=quad*4+rg within ct*16
        int mG = m0 + w * 16 + lo;
#pragma unroll
        for (int ct = 0; ct < 4; ++ct) {
            int cG = ct * 16 + quad * 4;
#pragma unroll
            for (int rg = 0; rg < 4; ++rg)
                outG[((size_t)b * 64 + cG + rg) * Mp + mG] = f2b(accG[ct][rg]);
        }
    }
}

// ---------------- K2: batched MFMA flash attention (all 5 iters) ----------------
// grid = 5 * 288 = 1440, block = 256
__global__ __launch_bounds__(256) void k_attn(const short* __restrict__ tq,
                                              const short* __restrict__ PTb,
                                              const short* __restrict__ GTb,
                                              float* __restrict__ OUT) {
    const int AM[5]   = {2304, 2304, 576, 144, 36};
    const int AMp[5]  = {2304, 2304, 576, 192, 64};
    const int APOFF[5] = {0, 589824, 1179648, 1327104, 1376256};

    __shared__ __align__(16) short s_P[32][72];
    __shared__ float s_red[4][32];
    __shared__ float s_red2[4][32];
    __shared__ float s_alpha[32];
    __shared__ float s_lf[32];

    int t = threadIdx.x;
    int seg = blockIdx.x / 288;
    int r = blockIdx.x % 288;
    int b = r / 72;
    int n0 = (r % 72) * 32;
    int M = AM[seg], Mp = AMp[seg];
    const short* pT = PTb + APOFF[seg];
    const short* gT = GTb + APOFF[seg];
    float* outm = OUT + (size_t)seg * 589824;

    int w = t >> 6, lane = t & 63, lo = lane & 15, quad = lane >> 4;

    const short* tqB = tq + ((size_t)b * NN + n0 + lo) * 64 + quad * 8;
    bf16x8 bq[2][2];
#pragma unroll
    for (int i = 0; i < 2; ++i)
#pragma unroll
        for (int h = 0; h < 2; ++h)
            bq[i][h] = *(const bf16x8*)(tqB + i * 16 * 64 + h * 32);

    const short* pA = pT + ((size_t)b * Mp + w * 16 + lo) * 64 + quad * 8;
    const short* gB = gT + ((size_t)b * 64 + w * 16 + lo) * Mp + quad * 8;

    bf16x8 pa0 = *(const bf16x8*)(pA);
    bf16x8 pa1 = *(const bf16x8*)(pA + 32);
    bf16x8 gb0 = *(const bf16x8*)(gB);
    bf16x8 gb1 = *(const bf16x8*)(gB + 32);

    f32x4 accO[2];
    accO[0] = f32x4{0.f, 0.f, 0.f, 0.f};
    accO[1] = f32x4{0.f, 0.f, 0.f, 0.f};
    float m_run[2] = {-1e30f, -1e30f}, l_run[2] = {0.f, 0.f};

    int nch = Mp >> 6;
    for (int ch = 0; ch < nch; ++ch) {
        int m0 = ch << 6;
        bf16x8 pa0n, pa1n, gb0n, gb1n;
        bool more = (ch + 1 < nch);
        if (more) {
            int mn = m0 + 64;
            pa0n = *(const bf16x8*)(pA + (size_t)mn * 64);
            pa1n = *(const bf16x8*)(pA + (size_t)mn * 64 + 32);
            gb0n = *(const bf16x8*)(gB + mn);
            gb1n = *(const bf16x8*)(gB + mn + 32);
        }
        f32x4 S[2];
        S[0] = f32x4{0.f, 0.f, 0.f, 0.f};
        S[0] = __builtin_amdgcn_mfma_f32_16x16x32_bf16(pa0, bq[0][0], S[0], 0, 0, 0);
        S[0] = __builtin_amdgcn_mfma_f32_16x16x32_bf16(pa1, bq[0][1], S[0], 0, 0, 0);
        S[1] = f32x4{0.f, 0.f, 0.f, 0.f};
        S[1] = __builtin_amdgcn_mfma_f32_16x16x32_bf16(pa0, bq[1][0], S[1], 0, 0, 0);
        S[1] = __builtin_amdgcn_mfma_f32_16x16x32_bf16(pa1, bq[1][1], S[1], 0, 0, 0);
        float cm[2] = {-1e30f, -1e30f};
#pragma unroll
        for (int rg = 0; rg < 4; ++rg) {
            int mglob = m0 + w * 16 + quad * 4 + rg;
            bool oob = mglob >= M;
#pragma unroll
            for (int i = 0; i < 2; ++i) {
                if (oob) S[i][rg] = -1e30f;
                cm[i] = fmaxf(cm[i], S[i][rg]);
            }
        }
#pragma unroll
        for (int i = 0; i < 2; ++i) {
            cm[i] = fmaxf(cm[i], __shfl_xor(cm[i], 16, 64));
            cm[i] = fmaxf(cm[i], __shfl_xor(cm[i], 32, 64));
        }
        if (lane < 16) { s_red[w][lo] = cm[0]; s_red[w][16 + lo] = cm[1]; }
        __syncthreads();
        float al[2];
#pragma unroll
        for (int i = 0; i < 2; ++i) {
            int n = i * 16 + lo;
            float chm = fmaxf(fmaxf(s_red[0][n], s_red[1][n]),
                              fmaxf(s_red[2][n], s_red[3][n]));
            float mn_ = fmaxf(m_run[i], chm);
            al[i] = __expf(m_run[i] - mn_);
            m_run[i] = mn_;
            float ps = 0.f;
            short4 pw;
#pragma unroll
            for (int rg = 0; rg < 4; ++rg) {
                float e = __expf(S[i][rg] - mn_);
                ps += e;
                ((short*)&pw)[rg] = f2b(e);
            }
            ps += __shfl_xor(ps, 16, 64);
            ps += __shfl_xor(ps, 32, 64);
            if (lane < 16) s_red2[w][n] = ps;
            *(short4*)&s_P[n][w * 16 + quad * 4] = pw;
        }
        if (w == 0 && lane < 16) { s_alpha[lo] = al[0]; s_alpha[16 + lo] = al[1]; }
        __syncthreads();
#pragma unroll
        for (int i = 0; i < 2; ++i) {
            int n = i * 16 + lo;
            l_run[i] = l_run[i] * al[i] +
                       (s_red2[0][n] + s_red2[1][n] + s_red2[2][n] + s_red2[3][n]);
#pragma unroll
            for (int rg = 0; rg < 4; ++rg)
                accO[i][rg] *= s_alpha[i * 16 + quad * 4 + rg];
            const bf16x8 a0 = *(const bf16x8*)&s_P[n][quad * 8];
            const bf16x8 a1 = *(const bf16x8*)&s_P[n][32 + quad * 8];
            accO[i] = __builtin_amdgcn_mfma_f32_16x16x32_bf16(a0, gb0, accO[i], 0, 0, 0);
            accO[i] = __builtin_amdgcn_mfma_f32_16x16x32_bf16(a1, gb1, accO[i], 0, 0, 0);
        }
        if (more) { pa0 = pa0n; pa1 = pa1n; gb0 = gb0n; gb1 = gb1n; }
    }
    if (w == 0 && lane < 16) { s_lf[lo] = l_run[0]; s_lf[16 + lo] = l_run[1]; }
    __syncthreads();
#pragma unroll
    for (int i = 0; i < 2; ++i)
#pragma unroll
        for (int rg = 0; rg < 4; ++rg) {
            int n = i * 16 + quad * 4 + rg;
            outm[((size_t)b * NN + n0 + n) * 64 + w * 16 + lo] = accO[i][rg] / s_lf[n];
        }
}

// ---------------- K3: MFMA z-conv + fused BN stats ----------------
// V_b[cp][sp] = flat[cp*2304+sp] (the "wrong reshape" is a free reinterpretation).
// Z_b = z_w(256x64) . V_b(64x2304). grid = 5*4*36 = 720, block = 256.
__global__ __launch_bounds__(256) void k_z(const float* __restrict__ OUT,
                                           const short* __restrict__ ZWb,
                                           short* __restrict__ Zb,
                                           float* __restrict__ STATS) {
    __shared__ __align__(16) short s_ut[64][72];   // V^T tile: [sp][cp] bf16
    int t = threadIdx.x;
    int seg = blockIdx.x / 144;
    int r = blockIdx.x % 144;
    int b = r / 36;
    int sp0 = (r % 36) * 64;
    const float* F = OUT + (size_t)seg * 589824 + (size_t)b * 147456;
    short* z = Zb + (size_t)seg * 2359296 + (size_t)b * 589824;
    float* stats = STATS + seg * 512;

    int w = t >> 6, lane = t & 63, lo = lane & 15, quad = lane >> 4;

    bf16x8 af[4][2];
#pragma unroll
    for (int qt = 0; qt < 4; ++qt)
#pragma unroll
        for (int h = 0; h < 2; ++h)
            af[qt][h] = *(const bf16x8*)&ZWb[(size_t)(w * 64 + qt * 16 + lo) * 64 + h * 32 + quad * 8];

#pragma unroll
    for (int rr = 0; rr < 4; ++rr) {
        int idx = t + rr * 256;
        int spl = idx & 63;
        int cp0 = (idx >> 6) << 2;
        short4 pk;
        pk.x = f2b(F[(size_t)(cp0 + 0) * 2304 + sp0 + spl]);
        pk.y = f2b(F[(size_t)(cp0 + 1) * 2304 + sp0 + spl]);
        pk.z = f2b(F[(size_t)(cp0 + 2) * 2304 + sp0 + spl]);
        pk.w = f2b(F[(size_t)(cp0 + 3) * 2304 + sp0 + spl]);
        *(short4*)&s_ut[spl][cp0] = pk;
    }
    __syncthreads();

    bf16x8 bfr[4][2];
#pragma unroll
    for (int st = 0; st < 4; ++st)
#pragma unroll
        for (int h = 0; h < 2; ++h)
            bfr[st][h] = *(const bf16x8*)&s_ut[st * 16 + lo][h * 32 + quad * 8];

    f32x4 acc[4][4];
#pragma unroll
    for (int qt = 0; qt < 4; ++qt)
#pragma unroll
        for (int st = 0; st < 4; ++st) {
            acc[qt][st] = f32x4{0.f, 0.f, 0.f, 0.f};
            acc[qt][st] = __builtin_amdgcn_mfma_f32_16x16x32_bf16(af[qt][0], bfr[st][0], acc[qt][st], 0, 0, 0);
            acc[qt][st] = __builtin_amdgcn_mfma_f32_16x16x32_bf16(af[qt][1], bfr[st][1], acc[qt][st], 0, 0, 0);
        }

#pragma unroll
    for (int qt = 0; qt < 4; ++qt) {
        float s1[4] = {0.f, 0.f, 0.f, 0.f};
        float s2[4] = {0.f, 0.f, 0.f, 0.f};
        int qb = w * 64 + qt * 16 + quad * 4;
#pragma unroll
        for (int st = 0; st < 4; ++st) {
            int sp = sp0 + st * 16 + lo;
#pragma unroll
            for (int rg = 0; rg < 4; ++rg) {
                float v = acc[qt][st][rg];
                z[(size_t)(qb + rg) * 2304 + sp] = f2b(v);
                s1[rg] += v;
                s2[rg] += v * v;
            }
        }
#pragma unroll
        for (int rg = 0; rg < 4; ++rg) {
            for (int o = 8; o >= 1; o >>= 1) {
                s1[rg] += __shfl_xor(s1[rg], o, 16);
                s2[rg] += __shfl_xor(s2[rg], o, 16);
            }
            if (lo == 0) {
                atomicAdd(&stats[(qb + rg) * 2], s1[rg]);
                atomicAdd(&stats[(qb + rg) * 2 + 1], s2[rg]);
            }
        }
    }
}

// ---------------- K4: final BN-normalize-and-sum over 5 iterations ----------------
// grid = 9216 x 256 = 2359296 exactly
__global__ __launch_bounds__(256) void k_final(
    const short* __restrict__ Zb, const float* __restrict__ STATS,
    const float* g0, const float* g1, const float* g2, const float* g3, const float* g4,
    const float* b0, const float* b1, const float* b2, const float* b3, const float* b4,
    float* __restrict__ outp) {
    int idx = blockIdx.x * 256 + threadIdx.x;
    int q = (idx / NN) & 255;
    const float inv = 1.f / (float)(BB * NN);
    float o = 0.f;
#pragma unroll
    for (int i = 0; i < 5; ++i) {
        float mean = STATS[i * 512 + q * 2] * inv;
        float var = STATS[i * 512 + q * 2 + 1] * inv - mean * mean;
        float rr = rsqrtf(var + 1e-5f);
        float zv = b2f16(Zb[(size_t)i * 2359296 + idx]);
        const float* gm = (i == 0) ? g0 : (i == 1) ? g1 : (i == 2) ? g2 : (i == 3) ? g3 : g4;
        const float* bt = (i == 0) ? b0 : (i == 1) ? b1 : (i == 2) ? b2 : (i == 3) ? b3 : b4;
        o += (zv - mean) * rr * gm[q] + bt[q];
    }
    outp[idx] = o;
}

extern "C" void kernel_launch(void* const* d_in, const int* in_sizes, int n_in,
                              void* d_out, int out_size, void* d_ws, size_t ws_size,
                              hipStream_t stream) {
    const float* persp = (const float*)d_in[0];
    const float* resp[5];
    for (int i = 0; i < 5; ++i) resp[i] = (const float*)d_in[1 + i];
    const float* t_w = (const float*)d_in[6];
    const float* z_w = (const float*)d_in[7];
    const float *p_w[5], *g_w[5], *bng[5], *bnb[5];
    for (int i = 0; i < 5; ++i) {
        p_w[i] = (const float*)d_in[8 + 4 * i];
        g_w[i] = (const float*)d_in[9 + 4 * i];
        bng[i] = (const float*)d_in[10 + 4 * i];
        bnb[i] = (const float*)d_in[11 + 4 * i];
    }
    // workspace layout (shorts first, then floats)
    short* TQb = (short*)d_ws;              // 589824
    short* TWb = TQb + 589824;              // 16384
    short* ZWb = TWb + 16384;               // 16384
    short* WPb = ZWb + 16384;               // 249856
    short* WGb = WPb + 249856;              // 249856
    short* PTb = WGb + 249856;              // 1392640
    short* GTb = PTb + 1392640;             // 1392640
    short* Zb  = GTb + 1392640;             // 5 * 2359296 = 11796480
    float* OUT   = (float*)d_ws + 7852032;  // 5 * 589824 = 2949120 floats
    float* STATS = OUT + 2949120;           // 2560

    hipMemsetAsync(STATS, 0, 2560 * sizeof(float), stream);
    k_wcvt<<<2080, 256, 0, stream>>>(t_w, z_w,
        p_w[0], p_w[1], p_w[2], p_w[3], p_w[4],
        g_w[0], g_w[1], g_w[2], g_w[3], g_w[4],
        TWb, ZWb, WPb, WGb);
    k_conv<<<484, 256, 0, stream>>>(persp,
        resp[0], resp[1], resp[2], resp[3], resp[4],
        TWb, WPb, WGb, TQb, PTb, GTb);
    k_attn<<<1440, 256, 0, stream>>>(TQb, PTb, GTb, OUT);
    k_z<<<720, 256, 0, stream>>>(OUT, ZWb, Zb, STATS);
    k_final<<<9216, 256, 0, stream>>>(Zb, STATS,
        bng[0], bng[1], bng[2], bng[3], bng[4],
        bnb[0], bnb[1], bnb[2], bnb[3], bnb[4],
        (float*)d_out);
}

// Round 8
// 290.517 us; speedup vs baseline: 1.3480x; 1.3480x over previous
//
#include <hip/hip_runtime.h>
#include <hip/hip_bf16.h>
#include <string.h>

#define BB 4
#define CPc 256
#define NN 2304   // 48*48

typedef __attribute__((ext_vector_type(8))) short bf16x8;
typedef __attribute__((ext_vector_type(4))) float f32x4;

__device__ __forceinline__ short f2b(float x) {
    __hip_bfloat16 h = __float2bfloat16(x);
    return *reinterpret_cast<short*>(&h);
}
__device__ __forceinline__ float b2f16(short v) {
    union { float f; unsigned u; } x;
    x.u = ((unsigned)(unsigned short)v) << 16;
    return x.f;
}

// ---------------- K0: convert weights fp32 -> bf16 ----------------
__global__ __launch_bounds__(256) void k_wcvt(
    const float* __restrict__ t_w, const float* __restrict__ z_w,
    const float* p0, const float* p1, const float* p2, const float* p3, const float* p4,
    const float* g0, const float* g1, const float* g2, const float* g3, const float* g4,
    short* __restrict__ TWb, short* __restrict__ ZWb,
    short* __restrict__ WPb, short* __restrict__ WGb) {
    int idx = blockIdx.x * 256 + threadIdx.x;
    if (idx < 16384) { TWb[idx] = f2b(t_w[idx]); return; }
    if (idx < 32768) { ZWb[idx - 16384] = f2b(z_w[idx - 16384]); return; }
    int k = idx - 32768;
    bool isP = k < 249856;
    if (!isP) k -= 249856;
    int i, off;
    if (k < 4096)        { i = 0; off = 0; }
    else if (k < 20480)  { i = 1; off = 4096; }
    else if (k < 53248)  { i = 2; off = 20480; }
    else if (k < 118784) { i = 3; off = 53248; }
    else                 { i = 4; off = 118784; }
    const float* s;
    if (isP) s = (i == 0) ? p0 : (i == 1) ? p1 : (i == 2) ? p2 : (i == 3) ? p3 : p4;
    else     s = (i == 0) ? g0 : (i == 1) ? g1 : (i == 2) ? g2 : (i == 3) ? g3 : g4;
    (isP ? WPb : WGb)[k] = f2b(s[k - off]);
}

// ---------------- K1: batched MFMA 1x1 convs, LDS-staged, SPLIT-K ----------------
// Every block handles <=4 k-chunks (256 k max). Segs 3/4/5 split Cr into 2/4/8
// slices writing fp32 partials; k_cvt reduces. Segs 0-2 write bf16 directly.
// blocks/seg = 4b * mtiles * kslices: {144,144,144,72,48,32} cum->584
__global__ __launch_bounds__(256) void k_conv(
    const float* __restrict__ persp,
    const float* r0, const float* r1, const float* r2, const float* r3, const float* r4,
    const short* __restrict__ TWb, const short* __restrict__ WPb, const short* __restrict__ WGb,
    short* __restrict__ TQb, short* __restrict__ PTb, short* __restrict__ GTb,
    float* __restrict__ PPART, float* __restrict__ GPART) {
    const int CUM[7]  = {0, 144, 288, 432, 504, 552, 584};
    const int CRs[6]  = {256, 64, 256, 512, 1024, 2048};
    const int Mus[6]  = {2304, 2304, 2304, 576, 144, 36};
    const int Mps[6]  = {2304, 2304, 2304, 576, 192, 64};
    const int KSs[6]  = {1, 1, 1, 2, 4, 8};
    const int WOFF[6] = {0, 0, 4096, 20480, 53248, 118784};
    const int POFF[6] = {0, 0, 589824, 1179648, 1327104, 1376256};
    const int PBASE[6] = {0, 0, 0, 0, 294912, 491520};   // partial-buffer base (segs 3..5)

    __shared__ __align__(16) short s_a[64][72];   // [m][k] bf16, k-group XOR-swizzled

    int blk = blockIdx.x, t = threadIdx.x;
    int w = t >> 6, lane = t & 63, lo = lane & 15, quad = lane >> 4;
    int seg = 0;
#pragma unroll
    for (int s_ = 1; s_ <= 5; ++s_) if (blk >= CUM[s_]) seg = s_;
    int Cr = CRs[seg], M = Mus[seg], Mp = Mps[seg], KS = KSs[seg];
    const float* in = (seg == 0) ? persp : (seg == 1) ? r0 : (seg == 2) ? r1 :
                      (seg == 3) ? r2 : (seg == 4) ? r3 : r4;
    const short* wp = (seg == 0) ? TWb : WPb + WOFF[seg];
    const short* wg = WGb + WOFF[seg];
    bool has_g = (seg != 0);
    int local = blk - CUM[seg];
    int mt = Mp >> 6;
    int b = local / (mt * KS);
    int rem = local % (mt * KS);
    int m0 = (rem / KS) * 64;
    int ksi = rem % KS;
    int kLen = Cr / KS, k0 = ksi * kLen;

    int ml = t & 63;                     // staged m within tile (lane = contiguous dim)
    int ssw = (ml >> 3) & 7;             // write-side swizzle
    bool mvalid = (m0 + ml) < M;
    const float* inB = in + ((size_t)b * Cr) * M + m0 + ml;

    int mrow = w * 16 + lo;              // A-frag row
    int rsw = (mrow >> 3) & 7;           // read-side swizzle

    f32x4 accP[4], accG[4];
#pragma unroll
    for (int ct = 0; ct < 4; ++ct) {
        accP[ct] = f32x4{0.f, 0.f, 0.f, 0.f};
        accG[ct] = f32x4{0.f, 0.f, 0.f, 0.f};
    }

    for (int kc = k0; kc < k0 + kLen; kc += 64) {
        __syncthreads();
#pragma unroll
        for (int r = 0; r < 8; ++r) {
            int kp = (t >> 6) + r * 4;   // k-pair 0..31
            int q = kp >> 2, l = kp & 3;
            float v0 = 0.f, v1 = 0.f;
            if (mvalid) {
                v0 = inB[(size_t)(kc + 2 * kp) * M];
                v1 = inB[(size_t)(kc + 2 * kp + 1) * M];
            }
            short2 pk; pk.x = f2b(v0); pk.y = f2b(v1);
            *(short2*)&s_a[ml][(q ^ ssw) * 8 + l * 2] = pk;
        }
        __syncthreads();
        const bf16x8 fr0 = *(const bf16x8*)&s_a[mrow][8 * (quad ^ rsw)];
        const bf16x8 fr1 = *(const bf16x8*)&s_a[mrow][8 * ((4 + quad) ^ rsw)];
#pragma unroll
        for (int ct = 0; ct < 4; ++ct) {
            const bf16x8 fp0 = *(const bf16x8*)&wp[(size_t)(ct * 16 + lo) * Cr + kc + quad * 8];
            const bf16x8 fp1 = *(const bf16x8*)&wp[(size_t)(ct * 16 + lo) * Cr + kc + 32 + quad * 8];
            accP[ct] = __builtin_amdgcn_mfma_f32_16x16x32_bf16(fr0, fp0, accP[ct], 0, 0, 0);
            accP[ct] = __builtin_amdgcn_mfma_f32_16x16x32_bf16(fr1, fp1, accP[ct], 0, 0, 0);
            if (has_g) {
                const bf16x8 fg0 = *(const bf16x8*)&wg[(size_t)(ct * 16 + lo) * Cr + kc + quad * 8];
                const bf16x8 fg1 = *(const bf16x8*)&wg[(size_t)(ct * 16 + lo) * Cr + kc + 32 + quad * 8];
                accG[ct] = __builtin_amdgcn_mfma_f32_16x16x32_bf16(fg0, fr0, accG[ct], 0, 0, 0);
                accG[ct] = __builtin_amdgcn_mfma_f32_16x16x32_bf16(fg1, fr1, accG[ct], 0, 0, 0);
            }
        }
    }
    if (KS == 1) {
        short* outP = (seg == 0) ? TQb : PTb + POFF[seg];
        short* outG = GTb + POFF[seg];
        int mP = m0 + w * 16 + quad * 4;
#pragma unroll
        for (int ct = 0; ct < 4; ++ct) {
            int c = ct * 16 + lo;
#pragma unroll
            for (int rg = 0; rg < 4; ++rg)
                outP[((size_t)b * Mp + mP + rg) * 64 + c] = f2b(accP[ct][rg]);
        }
        if (has_g) {
            int mG = m0 + w * 16 + lo;
#pragma unroll
            for (int ct = 0; ct < 4; ++ct) {
                int cG = ct * 16 + quad * 4;
#pragma unroll
                for (int rg = 0; rg < 4; ++rg)
                    outG[((size_t)b * 64 + cG + rg) * Mp + mG] = f2b(accG[ct][rg]);
            }
        }
    } else {
        // fp32 partials; slice stride = 4*Mp*64. P: [s][b][m][c], G: [s][b][c][m]
        int NP = 4 * Mp * 64;
        float* pp = PPART + PBASE[seg] + (size_t)ksi * NP;
        float* gp = GPART + PBASE[seg] + (size_t)ksi * NP;
        int mP = m0 + w * 16 + quad * 4;
#pragma unroll
        for (int ct = 0; ct < 4; ++ct) {
            int c = ct * 16 + lo;
#pragma unroll
            for (int rg = 0; rg < 4; ++rg)
                pp[((size_t)b * Mp + mP + rg) * 64 + c] = accP[ct][rg];
        }
        int mG = m0 + w * 16 + lo;
#pragma unroll
        for (int ct = 0; ct < 4; ++ct) {
            int cG = ct * 16 + quad * 4;
#pragma unroll
            for (int rg = 0; rg < 4; ++rg)
                gp[((size_t)b * 64 + cG + rg) * Mp + mG] = accG[ct][rg];
        }
    }
}

// ---------------- K1b: reduce split-K partials -> bf16 PTb/GTb ----------------
// Elements per seg (padded): seg3 147456, seg4 49152, seg5 16384 -> 212992 = 832*256.
// Two decodes so both P (c-fastest) and G (m-fastest) paths are coalesced.
__global__ __launch_bounds__(256) void k_cvt(const float* __restrict__ PPART,
                                             const float* __restrict__ GPART,
                                             short* __restrict__ PTb, short* __restrict__ GTb) {
    const int EC[4]    = {0, 147456, 196608, 212992};
    const int KSv[3]   = {2, 4, 8};
    const int PBASEv[3] = {0, 294912, 491520};
    const int POFFv[3] = {1179648, 1327104, 1376256};
    int e = blockIdx.x * 256 + threadIdx.x;
    int sg = (e < EC[1]) ? 0 : (e < EC[2]) ? 1 : 2;
    int rem = e - EC[sg];
    int KS = KSv[sg];
    int NP = (sg == 0) ? 147456 : (sg == 1) ? 49152 : 16384;   // 4*Mp*64
    // P path: inner index = rem (c fastest), slice-major sum
    {
        const float* src = PPART + PBASEv[sg] + rem;
        float p = 0.f;
        for (int s = 0; s < KS; ++s) p += src[(size_t)s * NP];
        PTb[POFFv[sg] + rem] = f2b(p);
    }
    // G path: same rem but interpreted m-fastest ([b][c][m])
    {
        const float* src = GPART + PBASEv[sg] + rem;
        float g = 0.f;
        for (int s = 0; s < KS; ++s) g += src[(size_t)s * NP];
        GTb[POFFv[sg] + rem] = f2b(g);
    }
}

// ---------------- K2: batched MFMA flash attention (all 5 iters) ----------------
// grid = 5 * 288 = 1440, block = 256
__global__ __launch_bounds__(256) void k_attn(const short* __restrict__ tq,
                                              const short* __restrict__ PTb,
                                              const short* __restrict__ GTb,
                                              float* __restrict__ OUT) {
    const int AM[5]   = {2304, 2304, 576, 144, 36};
    const int AMp[5]  = {2304, 2304, 576, 192, 64};
    const int APOFF[5] = {0, 589824, 1179648, 1327104, 1376256};

    __shared__ __align__(16) short s_P[32][72];
    __shared__ float s_red[4][32];
    __shared__ float s_red2[4][32];
    __shared__ float s_alpha[32];
    __shared__ float s_lf[32];

    int t = threadIdx.x;
    int seg = blockIdx.x / 288;
    int r = blockIdx.x % 288;
    int b = r / 72;
    int n0 = (r % 72) * 32;
    int M = AM[seg], Mp = AMp[seg];
    const short* pT = PTb + APOFF[seg];
    const short* gT = GTb + APOFF[seg];
    float* outm = OUT + (size_t)seg * 589824;

    int w = t >> 6, lane = t & 63, lo = lane & 15, quad = lane >> 4;

    const short* tqB = tq + ((size_t)b * NN + n0 + lo) * 64 + quad * 8;
    bf16x8 bq[2][2];
#pragma unroll
    for (int i = 0; i < 2; ++i)
#pragma unroll
        for (int h = 0; h < 2; ++h)
            bq[i][h] = *(const bf16x8*)(tqB + i * 16 * 64 + h * 32);

    const short* pA = pT + ((size_t)b * Mp + w * 16 + lo) * 64 + quad * 8;
    const short* gB = gT + ((size_t)b * 64 + w * 16 + lo) * Mp + quad * 8;

    bf16x8 pa0 = *(const bf16x8*)(pA);
    bf16x8 pa1 = *(const bf16x8*)(pA + 32);
    bf16x8 gb0 = *(const bf16x8*)(gB);
    bf16x8 gb1 = *(const bf16x8*)(gB + 32);

    f32x4 accO[2];
    accO[0] = f32x4{0.f, 0.f, 0.f, 0.f};
    accO[1] = f32x4{0.f, 0.f, 0.f, 0.f};
    float m_run[2] = {-1e30f, -1e30f}, l_run[2] = {0.f, 0.f};

    int nch = Mp >> 6;
    for (int ch = 0; ch < nch; ++ch) {
        int m0 = ch << 6;
        bf16x8 pa0n, pa1n, gb0n, gb1n;
        bool more = (ch + 1 < nch);
        if (more) {
            int mn = m0 + 64;
            pa0n = *(const bf16x8*)(pA + (size_t)mn * 64);
            pa1n = *(const bf16x8*)(pA + (size_t)mn * 64 + 32);
            gb0n = *(const bf16x8*)(gB + mn);
            gb1n = *(const bf16x8*)(gB + mn + 32);
        }
        f32x4 S[2];
        S[0] = f32x4{0.f, 0.f, 0.f, 0.f};
        S[0] = __builtin_amdgcn_mfma_f32_16x16x32_bf16(pa0, bq[0][0], S[0], 0, 0, 0);
        S[0] = __builtin_amdgcn_mfma_f32_16x16x32_bf16(pa1, bq[0][1], S[0], 0, 0, 0);
        S[1] = f32x4{0.f, 0.f, 0.f, 0.f};
        S[1] = __builtin_amdgcn_mfma_f32_16x16x32_bf16(pa0, bq[1][0], S[1], 0, 0, 0);
        S[1] = __builtin_amdgcn_mfma_f32_16x16x32_bf16(pa1, bq[1][1], S[1], 0, 0, 0);
        float cm[2] = {-1e30f, -1e30f};
#pragma unroll
        for (int rg = 0; rg < 4; ++rg) {
            int mglob = m0 + w * 16 + quad * 4 + rg;
            bool oob = mglob >= M;
#pragma unroll
            for (int i = 0; i < 2; ++i) {
                if (oob) S[i][rg] = -1e30f;
                cm[i] = fmaxf(cm[i], S[i][rg]);
            }
        }
#pragma unroll
        for (int i = 0; i < 2; ++i) {
            cm[i] = fmaxf(cm[i], __shfl_xor(cm[i], 16, 64));
            cm[i] = fmaxf(cm[i], __shfl_xor(cm[i], 32, 64));
        }
        if (lane < 16) { s_red[w][lo] = cm[0]; s_red[w][16 + lo] = cm[1]; }
        __syncthreads();
        float al[2];
#pragma unroll
        for (int i = 0; i < 2; ++i) {
            int n = i * 16 + lo;
            float chm = fmaxf(fmaxf(s_red[0][n], s_red[1][n]),
                              fmaxf(s_red[2][n], s_red[3][n]));
            float mn_ = fmaxf(m_run[i], chm);
            al[i] = __expf(m_run[i] - mn_);
            m_run[i] = mn_;
            float ps = 0.f;
            short4 pw;
#pragma unroll
            for (int rg = 0; rg < 4; ++rg) {
                float e = __expf(S[i][rg] - mn_);
                ps += e;
                ((short*)&pw)[rg] = f2b(e);
            }
            ps += __shfl_xor(ps, 16, 64);
            ps += __shfl_xor(ps, 32, 64);
            if (lane < 16) s_red2[w][n] = ps;
            *(short4*)&s_P[n][w * 16 + quad * 4] = pw;
        }
        if (w == 0 && lane < 16) { s_alpha[lo] = al[0]; s_alpha[16 + lo] = al[1]; }
        __syncthreads();
#pragma unroll
        for (int i = 0; i < 2; ++i) {
            int n = i * 16 + lo;
            l_run[i] = l_run[i] * al[i] +
                       (s_red2[0][n] + s_red2[1][n] + s_red2[2][n] + s_red2[3][n]);
#pragma unroll
            for (int rg = 0; rg < 4; ++rg)
                accO[i][rg] *= s_alpha[i * 16 + quad * 4 + rg];
            const bf16x8 a0 = *(const bf16x8*)&s_P[n][quad * 8];
            const bf16x8 a1 = *(const bf16x8*)&s_P[n][32 + quad * 8];
            accO[i] = __builtin_amdgcn_mfma_f32_16x16x32_bf16(a0, gb0, accO[i], 0, 0, 0);
            accO[i] = __builtin_amdgcn_mfma_f32_16x16x32_bf16(a1, gb1, accO[i], 0, 0, 0);
        }
        if (more) { pa0 = pa0n; pa1 = pa1n; gb0 = gb0n; gb1 = gb1n; }
    }
    if (w == 0 && lane < 16) { s_lf[lo] = l_run[0]; s_lf[16 + lo] = l_run[1]; }
    __syncthreads();
#pragma unroll
    for (int i = 0; i < 2; ++i)
#pragma unroll
        for (int rg = 0; rg < 4; ++rg) {
            int n = i * 16 + quad * 4 + rg;
            outm[((size_t)b * NN + n0 + n) * 64 + w * 16 + lo] = accO[i][rg] / s_lf[n];
        }
}

// ---------------- K3: MFMA z-conv + fused BN stats ----------------
// grid = 5*4*36 = 720, block = 256
__global__ __launch_bounds__(256) void k_z(const float* __restrict__ OUT,
                                           const short* __restrict__ ZWb,
                                           short* __restrict__ Zb,
                                           float* __restrict__ STATS) {
    __shared__ __align__(16) short s_ut[64][72];
    int t = threadIdx.x;
    int seg = blockIdx.x / 144;
    int r = blockIdx.x % 144;
    int b = r / 36;
    int sp0 = (r % 36) * 64;
    const float* F = OUT + (size_t)seg * 589824 + (size_t)b * 147456;
    short* z = Zb + (size_t)seg * 2359296 + (size_t)b * 589824;
    float* stats = STATS + seg * 512;

    int w = t >> 6, lane = t & 63, lo = lane & 15, quad = lane >> 4;

    bf16x8 af[4][2];
#pragma unroll
    for (int qt = 0; qt < 4; ++qt)
#pragma unroll
        for (int h = 0; h < 2; ++h)
            af[qt][h] = *(const bf16x8*)&ZWb[(size_t)(w * 64 + qt * 16 + lo) * 64 + h * 32 + quad * 8];

#pragma unroll
    for (int rr = 0; rr < 4; ++rr) {
        int idx = t + rr * 256;
        int spl = idx & 63;
        int cp0 = (idx >> 6) << 2;
        short4 pk;
        pk.x = f2b(F[(size_t)(cp0 + 0) * 2304 + sp0 + spl]);
        pk.y = f2b(F[(size_t)(cp0 + 1) * 2304 + sp0 + spl]);
        pk.z = f2b(F[(size_t)(cp0 + 2) * 2304 + sp0 + spl]);
        pk.w = f2b(F[(size_t)(cp0 + 3) * 2304 + sp0 + spl]);
        *(short4*)&s_ut[spl][cp0] = pk;
    }
    __syncthreads();

    bf16x8 bfr[4][2];
#pragma unroll
    for (int st = 0; st < 4; ++st)
#pragma unroll
        for (int h = 0; h < 2; ++h)
            bfr[st][h] = *(const bf16x8*)&s_ut[st * 16 + lo][h * 32 + quad * 8];

    f32x4 acc[4][4];
#pragma unroll
    for (int qt = 0; qt < 4; ++qt)
#pragma unroll
        for (int st = 0; st < 4; ++st) {
            acc[qt][st] = f32x4{0.f, 0.f, 0.f, 0.f};
            acc[qt][st] = __builtin_amdgcn_mfma_f32_16x16x32_bf16(af[qt][0], bfr[st][0], acc[qt][st], 0, 0, 0);
            acc[qt][st] = __builtin_amdgcn_mfma_f32_16x16x32_bf16(af[qt][1], bfr[st][1], acc[qt][st], 0, 0, 0);
        }

#pragma unroll
    for (int qt = 0; qt < 4; ++qt) {
        float s1[4] = {0.f, 0.f, 0.f, 0.f};
        float s2[4] = {0.f, 0.f, 0.f, 0.f};
        int qb = w * 64 + qt * 16 + quad * 4;
#pragma unroll
        for (int st = 0; st < 4; ++st) {
            int sp = sp0 + st * 16 + lo;
#pragma unroll
            for (int rg = 0; rg < 4; ++rg) {
                float v = acc[qt][st][rg];
                z[(size_t)(qb + rg) * 2304 + sp] = f2b(v);
                s1[rg] += v;
                s2[rg] += v * v;
            }
        }
#pragma unroll
        for (int rg = 0; rg < 4; ++rg) {
            for (int o = 8; o >= 1; o >>= 1) {
                s1[rg] += __shfl_xor(s1[rg], o, 16);
                s2[rg] += __shfl_xor(s2[rg], o, 16);
            }
            if (lo == 0) {
                atomicAdd(&stats[(qb + rg) * 2], s1[rg]);
                atomicAdd(&stats[(qb + rg) * 2 + 1], s2[rg]);
            }
        }
    }
}

// ---------------- K4: final BN-normalize-and-sum over 5 iterations ----------------
__global__ __launch_bounds__(256) void k_final(
    const short* __restrict__ Zb, const float* __restrict__ STATS,
    const float* g0, const float* g1, const float* g2, const float* g3, const float* g4,
    const float* b0, const float* b1, const float* b2, const float* b3, const float* b4,
    float* __restrict__ outp) {
    int idx = blockIdx.x * 256 + threadIdx.x;
    int q = (idx / NN) & 255;
    const float inv = 1.f / (float)(BB * NN);
    float o = 0.f;
#pragma unroll
    for (int i = 0; i < 5; ++i) {
        float mean = STATS[i * 512 + q * 2] * inv;
        float var = STATS[i * 512 + q * 2 + 1] * inv - mean * mean;
        float rr = rsqrtf(var + 1e-5f);
        float zv = b2f16(Zb[(size_t)i * 2359296 + idx]);
        const float* gm = (i == 0) ? g0 : (i == 1) ? g1 : (i == 2) ? g2 : (i == 3) ? g3 : g4;
        const float* bt = (i == 0) ? b0 : (i == 1) ? b1 : (i == 2) ? b2 : (i == 3) ? b3 : b4;
        o += (zv - mean) * rr * gm[q] + bt[q];
    }
    outp[idx] = o;
}

extern "C" void kernel_launch(void* const* d_in, const int* in_sizes, int n_in,
                              void* d_out, int out_size, void* d_ws, size_t ws_size,
                              hipStream_t stream) {
    const float* persp = (const float*)d_in[0];
    const float* resp[5];
    for (int i = 0; i < 5; ++i) resp[i] = (const float*)d_in[1 + i];
    const float* t_w = (const float*)d_in[6];
    const float* z_w = (const float*)d_in[7];
    const float *p_w[5], *g_w[5], *bng[5], *bnb[5];
    for (int i = 0; i < 5; ++i) {
        p_w[i] = (const float*)d_in[8 + 4 * i];
        g_w[i] = (const float*)d_in[9 + 4 * i];
        bng[i] = (const float*)d_in[10 + 4 * i];
        bnb[i] = (const float*)d_in[11 + 4 * i];
    }
    // workspace layout (shorts first, then floats)
    short* TQb = (short*)d_ws;              // 589824
    short* TWb = TQb + 589824;              // 16384
    short* ZWb = TWb + 16384;               // 16384
    short* WPb = ZWb + 16384;               // 249856
    short* WGb = WPb + 249856;              // 249856
    short* PTb = WGb + 249856;              // 1392640
    short* GTb = PTb + 1392640;             // 1392640
    short* Zb  = GTb + 1392640;             // 5 * 2359296 = 11796480
    float* OUT   = (float*)d_ws + 7852032;  // 2949120 floats
    float* STATS = OUT + 2949120;           // 2560
    float* PPART = STATS + 2560;            // 622592 (2*147456 + 4*49152 + 8*16384)
    float* GPART = PPART + 622592;          // 622592

    hipMemsetAsync(STATS, 0, 2560 * sizeof(float), stream);
    k_wcvt<<<2080, 256, 0, stream>>>(t_w, z_w,
        p_w[0], p_w[1], p_w[2], p_w[3], p_w[4],
        g_w[0], g_w[1], g_w[2], g_w[3], g_w[4],
        TWb, ZWb, WPb, WGb);
    k_conv<<<584, 256, 0, stream>>>(persp,
        resp[0], resp[1], resp[2], resp[3], resp[4],
        TWb, WPb, WGb, TQb, PTb, GTb, PPART, GPART);
    k_cvt<<<832, 256, 0, stream>>>(PPART, GPART, PTb, GTb);
    k_attn<<<1440, 256, 0, stream>>>(TQb, PTb, GTb, OUT);
    k_z<<<720, 256, 0, stream>>>(OUT, ZWb, Zb, STATS);
    k_final<<<9216, 256, 0, stream>>>(Zb, STATS,
        bng[0], bng[1], bng[2], bng[3], bng[4],
        bnb[0], bnb[1], bnb[2], bnb[3], bnb[4],
        (float*)d_out);
}